// Round 1
// baseline (375.622 us; speedup 1.0000x reference)
//
#include <hip/hip_runtime.h>

#define B        256
#define MAX_LEN  1024
#define FDIM     256

// Exclusive prefix sum of attr_len (B=256) -> starts, single block.
__global__ __launch_bounds__(B) void scan_starts_kernel(const int* __restrict__ attr_len,
                                                        int* __restrict__ starts) {
    __shared__ int buf[B];
    int t = threadIdx.x;
    int v = attr_len[t];
    buf[t] = v;
    __syncthreads();
    // Hillis-Steele inclusive scan
    for (int off = 1; off < B; off <<= 1) {
        int x = (t >= off) ? buf[t - off] : 0;
        __syncthreads();
        buf[t] += x;
        __syncthreads();
    }
    starts[t] = buf[t] - v;  // exclusive scan
}

// One wave (64 lanes) per output row of 256 floats; lane handles one float4.
// Gather form: writes every output element exactly once (data or zero).
__global__ __launch_bounds__(256) void gather_rows_kernel(const float* __restrict__ attr,
                                                          const int* __restrict__ attr_len,
                                                          const int* __restrict__ starts,
                                                          float* __restrict__ out) {
    const int wave = (int)((blockIdx.x * blockDim.x + threadIdx.x) >> 6);  // global wave id = output row
    const int lane = threadIdx.x & 63;
    const int b = wave >> 10;      // row / MAX_LEN
    const int i = wave & 1023;     // row % MAX_LEN

    float4 val = make_float4(0.f, 0.f, 0.f, 0.f);
    const int len = attr_len[b];   // wave-uniform
    if (i < len) {
        const int src = starts[b] + i;
        val = *(const float4*)(attr + (size_t)src * FDIM + (size_t)lane * 4);
    }
    *(float4*)(out + (size_t)wave * FDIM + (size_t)lane * 4) = val;
}

extern "C" void kernel_launch(void* const* d_in, const int* in_sizes, int n_in,
                              void* d_out, int out_size, void* d_ws, size_t ws_size,
                              hipStream_t stream) {
    const float* attr     = (const float*)d_in[0];
    // d_in[1] = graph_id_attr (int32) -- not needed: graphs are stored contiguously,
    // so out[g, i] = attr[starts[g] + i], derived from attr_len alone.
    const int*   attr_len = (const int*)d_in[2];
    float*       out      = (float*)d_out;
    int*         starts   = (int*)d_ws;  // B ints of scratch

    scan_starts_kernel<<<1, B, 0, stream>>>(attr_len, starts);

    // B*MAX_LEN rows, one wave each, 4 waves per 256-thread block.
    const int total_waves = B * MAX_LEN;          // 262144
    const int blocks = total_waves / 4;           // 65536
    gather_rows_kernel<<<blocks, 256, 0, stream>>>(attr, attr_len, starts, out);
}

// Round 2
// 365.577 us; speedup vs baseline: 1.0275x; 1.0275x over previous
//
#include <hip/hip_runtime.h>

#define NGRAPH   256
#define MAX_LEN  1024
#define FDIM     256

// Fused kernel: one wave (64 lanes) per output row of 256 floats.
// Each wave recomputes its graph's exclusive-prefix start from attr_len
// (4 coalesced L1-hot loads + 6-step shuffle butterfly) -- cheaper than a
// separate scan kernel + inter-kernel dependency, and fully hidden under
// the streaming float4 stores.
__global__ __launch_bounds__(256) void gather_rows_fused(const float* __restrict__ attr,
                                                         const int* __restrict__ attr_len,
                                                         float* __restrict__ out) {
    const int wave_in_block = threadIdx.x >> 6;
    const int lane = threadIdx.x & 63;
    const int row  = blockIdx.x * 4 + wave_in_block;   // output row in [0, NGRAPH*MAX_LEN)
    const int b    = row >> 10;                        // graph id
    const int i    = row & (MAX_LEN - 1);              // position within graph

    // start = sum_{g < b} attr_len[g]; len = attr_len[b]
    int partial = 0;
#pragma unroll
    for (int c = 0; c < 4; ++c) {
        const int g = c * 64 + lane;                   // covers 0..255
        const int v = attr_len[g];                     // coalesced, L1-hot
        partial += (g < b) ? v : 0;
    }
#pragma unroll
    for (int off = 32; off > 0; off >>= 1)
        partial += __shfl_xor(partial, off, 64);
    const int start = partial;                         // uniform across wave
    const int len   = attr_len[b];

    float4 val = make_float4(0.f, 0.f, 0.f, 0.f);
    if (i < len) {
        val = *(const float4*)(attr + (size_t)(start + i) * FDIM + (size_t)lane * 4);
    }
    *(float4*)(out + (size_t)row * FDIM + (size_t)lane * 4) = val;
}

extern "C" void kernel_launch(void* const* d_in, const int* in_sizes, int n_in,
                              void* d_out, int out_size, void* d_ws, size_t ws_size,
                              hipStream_t stream) {
    const float* attr     = (const float*)d_in[0];
    // d_in[1] = graph_id_attr -- unused: graphs are contiguous, so
    // out[g, i] = attr[start[g] + i] is derivable from attr_len alone.
    const int*   attr_len = (const int*)d_in[2];
    float*       out      = (float*)d_out;

    const int total_waves = NGRAPH * MAX_LEN;   // 262144 rows
    const int blocks = total_waves / 4;         // 4 waves per 256-thread block
    gather_rows_fused<<<blocks, 256, 0, stream>>>(attr, attr_len, out);
}